// Round 5
// baseline (275.470 us; speedup 1.0000x reference)
//
#include <hip/hip_runtime.h>
#include <math.h>

// B=32, C=3, H=W=512, window 11, sigma 1.5, VALID conv -> 502x502
#define H 512
#define W 512
#define OUT_H 502
#define OUT_W 502
#define C1c 1.0e-4f   // (0.01*1)^2
#define C2c 9.0e-4f   // (0.03*1)^2

#define TH 111            // output rows per block
#define NR 121            // TH+10 input rows = 11*11 (phase-exact)
#define HALO 10
#define SPAN 64           // output cols per WAVE (wave-private strip)
#define SLOTW 76          // 74 staged float4 entries + 2 pad, per wave

// Row-streaming SSIM with WAVE-PRIVATE staging — zero barriers in the row loop.
//  - each of the 4 waves owns a 64-col strip (+10 halo loaded by its own
//    lanes 0..9). LDS staging is wave-internal: DS ops from one wave execute
//    in program order, so write-row -> read-row needs no s_barrier and no
//    vmcnt(0)/lgkmcnt(0) drain (R0/R4 paid that drain EVERY row).
//  - single-slot stage buffer (no ring): in-order DS means row r's reads
//    retire before row r+1's write passes the pipe. wave_barrier() pins the
//    compiler's program order (zero hardware cost).
//  - staged quantities float4(x1, x2, x1*x2, x1^2); only x2^2 recomputed per
//    tap -> h-pass = 11 mul + 55 FMA (was 33 mul + 55 FMA). Reads are
//    lane-contiguous ds_read_b128 (conflict-free).
//  - 55 phase accumulators; cap stays 128 VGPR (R3 proved tighter caps spill).
//  - grid 2x5x96 = 960 blocks @ 4/CU -> one fully-resident round.
__global__ __launch_bounds__(256, 4)
void ssim_kernel(const float* __restrict__ img1,
                 const float* __restrict__ img2,
                 float* __restrict__ out) {
    __shared__ float4 stg[4][SLOTW];   // per-wave strips, 4864 B
    __shared__ float wsum[4];

    const int tid  = threadIdx.x;
    const int wid  = tid >> 6;
    const int lane = tid & 63;

    // Gaussian weights (runtime expf to match reference), pinned to SGPR
    float g[11];
    {
        float s = 0.f;
#pragma unroll
        for (int i = 0; i < 11; ++i) {
            float d = (float)(i - 5);
            g[i] = expf(-d * d * (1.0f / 4.5f));
            s += g[i];
        }
        float inv = 1.0f / s;
#pragma unroll
        for (int i = 0; i < 11; ++i) {
            g[i] *= inv;
            g[i] = __uint_as_float(__builtin_amdgcn_readfirstlane(__float_as_uint(g[i])));
        }
    }

    const int base = blockIdx.x * 256 + wid * SPAN;  // strip origin (0..448)
    const int oyb  = blockIdx.y * TH;                // output rows owned
    const int Y0   = min(oyb, H - NR);               // shift last tile up
    const int plane = blockIdx.z;                    // b*3 + c
    const size_t pbase = (size_t)plane * (H * W);
    const float* __restrict__ p1 = img1 + pbase;
    const float* __restrict__ p2 = img2 + pbase;

    const int gx = base + lane;                      // main column (<512)
    const int hx = min(base + SPAN + lane, W - 1);   // halo column (lanes<10)
    const float cmask = (gx < OUT_W) ? 1.0f : 0.0f;  // discard cols 502..511
    const bool hl = (lane < HALO);

    float4* const st = stg[wid];

    // 11 phase slots of vertical partial sums, 5 quantities
    float a0[11], a1[11], a2[11], a3[11], a4[11];
#pragma unroll
    for (int i = 0; i < 11; ++i) { a0[i]=0.f; a1[i]=0.f; a2[i]=0.f; a3[i]=0.f; a4[i]=0.f; }

    float lsum = 0.f;

    // wave-uniform row offset; capped advance keeps all loads in-bounds
    int ro = Y0 * W;
    const int rocap = (H - 1) * W;

    // prime prefetch (row Y0)
    float m1v = p1[ro + gx], m2v = p2[ro + gx];
    float h1v = 0.f, h2v = 0.f;
    if (hl) { h1v = p1[ro + hx]; h2v = p2[ro + hx]; }

#pragma unroll 1
    for (int rb = 0; rb < NR; rb += 11) {
#pragma unroll
        for (int p = 0; p < 11; ++p) {
            const int r = rb + p;

            // stage row r: (x1, x2, x1*x2, x1^2) — products once per element
            st[lane] = make_float4(m1v, m2v, m1v * m2v, m1v * m1v);
            if (hl) st[SPAN + lane] = make_float4(h1v, h2v, h1v * h2v, h1v * h1v);

            // prefetch row r+1 (drains at NEXT row's ds_write via plain vmcnt)
            ro = min(ro + W, rocap);
            m1v = p1[ro + gx]; m2v = p2[ro + gx];
            if (hl) { h1v = p1[ro + hx]; h2v = p2[ro + hx]; }

            __builtin_amdgcn_wave_barrier();   // pin: writes/loads above, reads below

            // horizontal 11-tap conv; only q22 recomputed per tap
            float h0, h1, h2, h3, h4;
            {
                const float4* rp = st + lane;
#pragma unroll
                for (int t = 0; t < 11; ++t) {
                    const float4 v = rp[t];        // ds_read_b128, offset t*16
                    const float w = g[t];
                    const float q22 = v.y * v.y;
                    if (t == 0) {
                        h0 = w * v.x; h1 = w * v.y; h2 = w * v.w;
                        h3 = w * q22; h4 = w * v.z;
                    } else {
                        h0 = fmaf(w, v.x, h0);    // conv(x1)
                        h1 = fmaf(w, v.y, h1);    // conv(x2)
                        h2 = fmaf(w, v.w, h2);    // conv(x1^2)
                        h3 = fmaf(w, q22, h3);    // conv(x2^2)
                        h4 = fmaf(w, v.z, h4);    // conv(x1*x2)
                    }
                }
            }

            __builtin_amdgcn_wave_barrier();   // pin: reads above next row's writes

            // vertical scatter: slot a==p was flushed last row -> first write is mul
#pragma unroll
            for (int a = 0; a < 11; ++a) {
                const float w = g[(p - a + 11) % 11];   // compile-time -> SGPR
                if (a == p) {
                    a0[a] = w * h0; a1[a] = w * h1; a2[a] = w * h2;
                    a3[a] = w * h3; a4[a] = w * h4;
                } else {
                    a0[a] = fmaf(w, h0, a0[a]); a1[a] = fmaf(w, h1, a1[a]);
                    a2[a] = fmaf(w, h2, a2[a]); a3[a] = fmaf(w, h3, a3[a]);
                    a4[a] = fmaf(w, h4, a4[a]);
                }
            }

            // output row oy = Y0 + r - 10 completes in slot e = (p+1)%11
            if (r >= 10) {
                const int e = (p + 1) % 11;
                const int oy = Y0 + r - 10;            // uniform (SALU)
                if (oy >= oyb) {                       // ownership (de-dup last tile)
                    const float m1 = a0[e], m2 = a1[e];
                    const float m1s = m1 * m1, m2s = m2 * m2, m12 = m1 * m2;
                    const float sig1  = a2[e] - m1s;
                    const float sig2  = a3[e] - m2s;
                    const float sig12 = a4[e] - m12;
                    const float num = (2.f * m12 + C1c) * (2.f * sig12 + C2c);
                    const float den = (m1s + m2s + C1c) * (sig1 + sig2 + C2c);
                    const float v = num * __builtin_amdgcn_rcpf(den);
                    lsum = fmaf(cmask, v, lsum);       // predication via mask-FMA
                }
            }
        }
    }

    // per-wave reduce, then one cross-wave combine + one atomic per block
#pragma unroll
    for (int off = 32; off > 0; off >>= 1) lsum += __shfl_down(lsum, off, 64);
    if (lane == 0) wsum[wid] = lsum;
    __syncthreads();
    if (tid == 0) {
        const float inv_count = 1.0f / (3.0f * (float)OUT_H * (float)OUT_W);
        const float total = (wsum[0] + wsum[1] + wsum[2] + wsum[3]) * inv_count;
        atomicAdd(&out[plane / 3], total);
    }
}

__global__ void zero_out(float* out, int n) {
    int i = threadIdx.x + blockIdx.x * blockDim.x;
    if (i < n) out[i] = 0.f;
}

extern "C" void kernel_launch(void* const* d_in, const int* in_sizes, int n_in,
                              void* d_out, int out_size, void* d_ws, size_t ws_size,
                              hipStream_t stream) {
    const float* img1 = (const float*)d_in[0];
    const float* img2 = (const float*)d_in[1];
    float* out = (float*)d_out;

    zero_out<<<1, 64, 0, stream>>>(out, out_size);

    const int nplanes = in_sizes[0] / (H * W);          // 96
    dim3 grid(W / 256,                                  // 2 col-tiles (4 strips each)
              (OUT_H + TH - 1) / TH,                    // 5 row-tiles
              nplanes);                                 // 96 planes -> 960 blocks
    ssim_kernel<<<grid, 256, 0, stream>>>(img1, img2, out);
}